// Round 2
// baseline (942.057 us; speedup 1.0000x reference)
//
#include <hip/hip_runtime.h>

// Problem constants (fixed by the reference)
constexpr int BB = 32;     // batch
constexpr int DD = 384;    // latent dim
constexpr int TN = 4096;   // sequence length
constexpr int KK = 256;    // codebook size
constexpr float BETA = 0.25f;

constexpr int TT  = 64;           // tokens per block
constexpr int DG  = DD / 4;       // 96 float4 groups along D
constexpr int ECH = 4;            // dg-groups per LDS chunk
constexpr int NCH = DG / ECH;     // 24 chunks

constexpr size_t QSIZE = (size_t)BB * DD * TN;   // 50331648
constexpr size_t ISIZE = (size_t)BB * TN;        // 131072

// --- tiny pre-pass: per-code squared norms into workspace ---
__global__ void e2_kernel(const float* __restrict__ cb, float* __restrict__ e2) {
    int c = threadIdx.x;             // 256 threads == KK
    const float4* row = (const float4*)(cb + (size_t)c * DD);
    float s = 0.f;
    #pragma unroll
    for (int g = 0; g < DG; ++g) {
        float4 v = row[g];
        s += v.x * v.x + v.y * v.y + v.z * v.z + v.w * v.w;
    }
    e2[c] = s;
}

// --- main fused kernel: distances + argmin + quantize + indices + loss ---
// Thread tile 8 tokens x 8 codes: per dgl, 16 ds_read_b128 feed 256 v_fmac
// -> LDS demand 4 SIMD*16*10cyc = 640 vs 512 FMA cyc -> ~80% VALU ceiling
// (R1's 4x8 tile had 12 reads/128 FMA -> 53% ceiling, matched measured 54%).
__global__ __launch_bounds__(256, 3)
void vq_kernel(const float* __restrict__ z, const float* __restrict__ cb,
               const float* __restrict__ e2g, float* __restrict__ out) {
    __shared__ float4 es4[ECH][KK + 1];  // ~16 KB codebook chunk, [dgl][code] (+1: kill 4-way write conflict)
    __shared__ float4 xs4[ECH][TT];      //   4 KB z chunk, [dgl][token]
    __shared__ float  e2s[KK];           //   1 KB
    __shared__ int    idxs[TT];
    __shared__ float  wsum[4];

    const int tid = threadIdx.x;
    const int bid = blockIdx.x;
    const int b   = bid >> 6;                 // TN/TT = 64 tiles per batch
    const int t0  = (bid & 63) * TT;

    const int tx = tid & 31;                  // -> codes  c = tx + 32*j
    const int ty = tid >> 5;                  // -> tokens t = ty*8 + i  (ty 0..7)

    e2s[tid] = e2g[tid];

    const float*  zb  = z + (size_t)b * DD * TN + t0;
    const float4* cb4 = (const float4*)cb;

    // staging lane mapping
    const int ec   = tid >> 2;      // codebook: base row, 4 lanes share a 64B row segment
    const int edgl = tid & 3;
    const int xr   = tid >> 6;      // z: dgl row (0..3)
    const int xtt  = tid & 63;      // z: token (coalesced)

    // prefetch chunk 0 into registers
    float4 epf[4];
    float  xpf[4];
    #pragma unroll
    for (int s = 0; s < 4; ++s)
        epf[s] = cb4[(size_t)(ec + 64 * s) * DG + edgl];
    #pragma unroll
    for (int c = 0; c < 4; ++c)
        xpf[c] = zb[(size_t)(4 * xr + c) * TN + xtt];

    float acc[8][8];
    #pragma unroll
    for (int i = 0; i < 8; ++i)
        #pragma unroll
        for (int j = 0; j < 8; ++j) acc[i][j] = 0.f;

    for (int ch = 0; ch < NCH; ++ch) {
        __syncthreads();                     // prev-iter readers done
        #pragma unroll
        for (int s = 0; s < 4; ++s) es4[edgl][ec + 64 * s] = epf[s];
        xs4[xr][xtt] = make_float4(xpf[0], xpf[1], xpf[2], xpf[3]);
        __syncthreads();

        // prefetch chunk ch+1 (overlaps compute below)
        if (ch + 1 < NCH) {
            const int dgb = (ch + 1) * ECH;
            #pragma unroll
            for (int s = 0; s < 4; ++s)
                epf[s] = cb4[(size_t)(ec + 64 * s) * DG + dgb + edgl];
            #pragma unroll
            for (int c = 0; c < 4; ++c)
                xpf[c] = zb[(size_t)(4 * (dgb + xr) + c) * TN + xtt];
        }

        #pragma unroll
        for (int dgl = 0; dgl < ECH; ++dgl) {
            float4 xv[8];
            #pragma unroll
            for (int i = 0; i < 8; ++i) xv[i] = xs4[dgl][ty * 8 + i];  // broadcast
            #pragma unroll
            for (int j = 0; j < 8; ++j) {
                float4 ev = es4[dgl][tx + 32 * j];                     // contiguous b128
                #pragma unroll
                for (int i = 0; i < 8; ++i) {
                    acc[i][j] += xv[i].x * ev.x;
                    acc[i][j] += xv[i].y * ev.y;
                    acc[i][j] += xv[i].z * ev.z;
                    acc[i][j] += xv[i].w * ev.w;
                }
            }
        }
    }

    // per-thread argmin over its 8 codes (c ascending => first-min kept)
    float bv[8]; int bi[8];
    #pragma unroll
    for (int i = 0; i < 8; ++i) { bv[i] = 3.4e38f; bi[i] = 0x7fffffff; }
    #pragma unroll
    for (int j = 0; j < 8; ++j) {
        const int c = tx + 32 * j;
        const float e2c = e2s[c];
        #pragma unroll
        for (int i = 0; i < 8; ++i) {
            float v = e2c - 2.f * acc[i][j];    // x^2 constant per token: drop it
            if (v < bv[i]) { bv[i] = v; bi[i] = c; }
        }
    }
    // cross-lane reduce over the 32 tx lanes (lexicographic: val, then index)
    #pragma unroll
    for (int m = 16; m >= 1; m >>= 1) {
        #pragma unroll
        for (int i = 0; i < 8; ++i) {
            float ov = __shfl_xor(bv[i], m, 64);
            int   oi = __shfl_xor(bi[i], m, 64);
            if (ov < bv[i] || (ov == bv[i] && oi < bi[i])) { bv[i] = ov; bi[i] = oi; }
        }
    }
    if (tx == 0) {
        #pragma unroll
        for (int i = 0; i < 8; ++i) idxs[ty * 8 + i] = bi[i];
    }
    __syncthreads();

    // epilogue: quantize output (coalesced over t), loss partials
    {
        const int myi = idxs[xtt];
        const float4* crow = cb4 + (size_t)myi * DG;
        float* outq = out + (size_t)b * DD * TN + t0;
        float lsum = 0.f;
        #pragma unroll
        for (int m = 0; m < 24; ++m) {
            int dg = xr + 4 * m;
            float4 q = crow[dg];                               // L2-hot gather
            float x0 = zb[(size_t)(4 * dg + 0) * TN + xtt];    // coalesced re-read
            float x1 = zb[(size_t)(4 * dg + 1) * TN + xtt];
            float x2 = zb[(size_t)(4 * dg + 2) * TN + xtt];
            float x3 = zb[(size_t)(4 * dg + 3) * TN + xtt];
            float d0 = q.x - x0, d1 = q.y - x1, d2 = q.z - x2, d3 = q.w - x3;
            lsum += d0 * d0 + d1 * d1 + d2 * d2 + d3 * d3;
            outq[(size_t)(4 * dg + 0) * TN + xtt] = q.x;
            outq[(size_t)(4 * dg + 1) * TN + xtt] = q.y;
            outq[(size_t)(4 * dg + 2) * TN + xtt] = q.z;
            outq[(size_t)(4 * dg + 3) * TN + xtt] = q.w;
        }
        // indices output (as float: whole out buffer is fp32)
        if (tid < TT)
            out[QSIZE + (size_t)b * TN + t0 + tid] = (float)idxs[tid];

        // loss: wave reduce -> block reduce -> one atomic
        #pragma unroll
        for (int m = 32; m >= 1; m >>= 1) lsum += __shfl_xor(lsum, m, 64);
        if ((tid & 63) == 0) wsum[tid >> 6] = lsum;
        __syncthreads();
        if (tid == 0) {
            float s = wsum[0] + wsum[1] + wsum[2] + wsum[3];
            atomicAdd(out + QSIZE + ISIZE,
                      s * (BETA / (float)((size_t)BB * DD * TN)));
        }
    }
}

extern "C" void kernel_launch(void* const* d_in, const int* in_sizes, int n_in,
                              void* d_out, int out_size, void* d_ws, size_t ws_size,
                              hipStream_t stream) {
    (void)in_sizes; (void)n_in; (void)out_size; (void)ws_size;
    const float* z  = (const float*)d_in[0];
    const float* cb = (const float*)d_in[1];
    float* out  = (float*)d_out;
    float* e2ws = (float*)d_ws;

    // d_out is poisoned 0xAA before every timed launch: zero the loss slot
    hipMemsetAsync(out + QSIZE + ISIZE, 0, sizeof(float), stream);
    e2_kernel<<<dim3(1), dim3(256), 0, stream>>>(cb, e2ws);
    vq_kernel<<<dim3(BB * (TN / TT)), dim3(256), 0, stream>>>(z, cb, e2ws, out);
}

// Round 3
// 698.814 us; speedup vs baseline: 1.3481x; 1.3481x over previous
//
#include <hip/hip_runtime.h>

// Problem constants (fixed by the reference)
constexpr int BB = 32;     // batch
constexpr int DD = 384;    // latent dim
constexpr int TN = 4096;   // sequence length
constexpr int KK = 256;    // codebook size
constexpr float BETA = 0.25f;

constexpr int TT  = 64;           // tokens per block
constexpr int DG  = DD / 4;       // 96 float4 groups along D
constexpr int ECH = 4;            // dg-groups per LDS chunk
constexpr int NCH = DG / ECH;     // 24 chunks

constexpr size_t QSIZE = (size_t)BB * DD * TN;   // 50331648
constexpr size_t ISIZE = (size_t)BB * TN;        // 131072

// --- tiny pre-pass: per-code squared norms into workspace ---
__global__ void e2_kernel(const float* __restrict__ cb, float* __restrict__ e2) {
    int c = threadIdx.x;             // 256 threads == KK
    const float4* row = (const float4*)(cb + (size_t)c * DD);
    float s = 0.f;
    #pragma unroll
    for (int g = 0; g < DG; ++g) {
        float4 v = row[g];
        s += v.x * v.x + v.y * v.y + v.z * v.z + v.w * v.w;
    }
    e2[c] = s;
}

// --- main fused kernel: distances + argmin + quantize + indices + loss ---
// 8 tokens x 8 codes per thread: per dgl-step a wave does 8 contiguous
// ds_read_b128 (codes) + 8 broadcast b128 (tokens) feeding 256 v_fmac_f32.
// R2 lessons: NO padding on es4 (contiguous b128 is conflict-free, padding
// caused 6.3M conflicts) and NO long-lived prefetch regs (spilled acc to
// scratch: 1.3 GB of extra HBM writes). launch_bounds(256,2) = 256-reg
// budget so the 64 accumulators can never spill.
__global__ __launch_bounds__(256, 2)
void vq_kernel(const float* __restrict__ z, const float* __restrict__ cb,
               const float* __restrict__ e2g, float* __restrict__ out) {
    __shared__ float4 es4[ECH][KK];   // 16 KB codebook chunk, [dgl][code]
    __shared__ float4 xs4[ECH][TT];   //  4 KB z chunk, [dgl][token]
    __shared__ float  e2s[KK];        //  1 KB
    __shared__ int    idxs[TT];
    __shared__ float  wsum[4];

    const int tid = threadIdx.x;
    const int bid = blockIdx.x;
    const int b   = bid >> 6;                 // TN/TT = 64 tiles per batch
    const int t0  = (bid & 63) * TT;

    const int tx = tid & 31;                  // -> codes  c = tx + 32*j
    const int ty = tid >> 5;                  // -> tokens t = ty*8 + i

    e2s[tid] = e2g[tid];

    const float*  zb  = z + (size_t)b * DD * TN + t0;
    const float4* cb4 = (const float4*)cb;

    // staging lane mapping (transient loads each chunk, no cross-barrier regs)
    const int xr  = tid >> 6;      // z: dgl row (0..3)
    const int xtt = tid & 63;      // z: token (coalesced)

    float acc[8][8];
    #pragma unroll
    for (int i = 0; i < 8; ++i)
        #pragma unroll
        for (int j = 0; j < 8; ++j) acc[i][j] = 0.f;

    for (int ch = 0; ch < NCH; ++ch) {
        const int dgb = ch * ECH;
        // issue global loads first (overlap with other waves' compute)
        float4 ev0 = cb4[(size_t)tid * DG + dgb + 0];   // 64 contiguous B/row
        float4 ev1 = cb4[(size_t)tid * DG + dgb + 1];
        float4 ev2 = cb4[(size_t)tid * DG + dgb + 2];
        float4 ev3 = cb4[(size_t)tid * DG + dgb + 3];
        float x0 = zb[(size_t)(4 * (dgb + xr) + 0) * TN + xtt];  // coalesced
        float x1 = zb[(size_t)(4 * (dgb + xr) + 1) * TN + xtt];
        float x2 = zb[(size_t)(4 * (dgb + xr) + 2) * TN + xtt];
        float x3 = zb[(size_t)(4 * (dgb + xr) + 3) * TN + xtt];
        __syncthreads();                     // prev-iter readers done
        es4[0][tid] = ev0;                   // lane-contiguous b128 writes
        es4[1][tid] = ev1;
        es4[2][tid] = ev2;
        es4[3][tid] = ev3;
        xs4[xr][xtt] = make_float4(x0, x1, x2, x3);
        __syncthreads();

        #pragma unroll
        for (int dgl = 0; dgl < ECH; ++dgl) {
            float4 xv[8];
            #pragma unroll
            for (int i = 0; i < 8; ++i) xv[i] = xs4[dgl][ty * 8 + i];  // broadcast
            #pragma unroll
            for (int j = 0; j < 8; ++j) {
                float4 ev = es4[dgl][tx + 32 * j];                     // contiguous b128
                #pragma unroll
                for (int i = 0; i < 8; ++i) {
                    acc[i][j] += xv[i].x * ev.x;
                    acc[i][j] += xv[i].y * ev.y;
                    acc[i][j] += xv[i].z * ev.z;
                    acc[i][j] += xv[i].w * ev.w;
                }
            }
        }
    }

    // per-thread argmin over its 8 codes (c ascending => first-min kept)
    float bv[8]; int bi[8];
    #pragma unroll
    for (int i = 0; i < 8; ++i) { bv[i] = 3.4e38f; bi[i] = 0x7fffffff; }
    #pragma unroll
    for (int j = 0; j < 8; ++j) {
        const int c = tx + 32 * j;
        const float e2c = e2s[c];
        #pragma unroll
        for (int i = 0; i < 8; ++i) {
            float v = e2c - 2.f * acc[i][j];    // x^2 constant per token: drop it
            if (v < bv[i]) { bv[i] = v; bi[i] = c; }
        }
    }
    // cross-lane reduce over the 32 tx lanes (lexicographic: val, then index)
    #pragma unroll
    for (int m = 16; m >= 1; m >>= 1) {
        #pragma unroll
        for (int i = 0; i < 8; ++i) {
            float ov = __shfl_xor(bv[i], m, 64);
            int   oi = __shfl_xor(bi[i], m, 64);
            if (ov < bv[i] || (ov == bv[i] && oi < bi[i])) { bv[i] = ov; bi[i] = oi; }
        }
    }
    if (tx == 0) {
        #pragma unroll
        for (int i = 0; i < 8; ++i) idxs[ty * 8 + i] = bi[i];
    }
    __syncthreads();

    // epilogue: quantize output (coalesced over t), loss partials
    {
        const int myi = idxs[xtt];
        const float4* crow = cb4 + (size_t)myi * DG;
        float* outq = out + (size_t)b * DD * TN + t0;
        float lsum = 0.f;
        #pragma unroll
        for (int m = 0; m < 24; ++m) {
            int dg = xr + 4 * m;
            float4 q = crow[dg];                               // L2-hot gather
            float x0 = zb[(size_t)(4 * dg + 0) * TN + xtt];    // coalesced re-read
            float x1 = zb[(size_t)(4 * dg + 1) * TN + xtt];
            float x2 = zb[(size_t)(4 * dg + 2) * TN + xtt];
            float x3 = zb[(size_t)(4 * dg + 3) * TN + xtt];
            float d0 = q.x - x0, d1 = q.y - x1, d2 = q.z - x2, d3 = q.w - x3;
            lsum += d0 * d0 + d1 * d1 + d2 * d2 + d3 * d3;
            outq[(size_t)(4 * dg + 0) * TN + xtt] = q.x;
            outq[(size_t)(4 * dg + 1) * TN + xtt] = q.y;
            outq[(size_t)(4 * dg + 2) * TN + xtt] = q.z;
            outq[(size_t)(4 * dg + 3) * TN + xtt] = q.w;
        }
        // indices output (as float: whole out buffer is fp32)
        if (tid < TT)
            out[QSIZE + (size_t)b * TN + t0 + tid] = (float)idxs[tid];

        // loss: wave reduce -> block reduce -> one atomic
        #pragma unroll
        for (int m = 32; m >= 1; m >>= 1) lsum += __shfl_xor(lsum, m, 64);
        if ((tid & 63) == 0) wsum[tid >> 6] = lsum;
        __syncthreads();
        if (tid == 0) {
            float s = wsum[0] + wsum[1] + wsum[2] + wsum[3];
            atomicAdd(out + QSIZE + ISIZE,
                      s * (BETA / (float)((size_t)BB * DD * TN)));
        }
    }
}

extern "C" void kernel_launch(void* const* d_in, const int* in_sizes, int n_in,
                              void* d_out, int out_size, void* d_ws, size_t ws_size,
                              hipStream_t stream) {
    (void)in_sizes; (void)n_in; (void)out_size; (void)ws_size;
    const float* z  = (const float*)d_in[0];
    const float* cb = (const float*)d_in[1];
    float* out  = (float*)d_out;
    float* e2ws = (float*)d_ws;

    // d_out is poisoned 0xAA before every timed launch: zero the loss slot
    hipMemsetAsync(out + QSIZE + ISIZE, 0, sizeof(float), stream);
    e2_kernel<<<dim3(1), dim3(256), 0, stream>>>(cb, e2ws);
    vq_kernel<<<dim3(BB * (TN / TT)), dim3(256), 0, stream>>>(z, cb, e2ws, out);
}